// Round 16
// baseline (139.030 us; speedup 1.0000x reference)
//
#include <hip/hip_runtime.h>

typedef float f32x4 __attribute__((ext_vector_type(4)));
typedef short short8 __attribute__((ext_vector_type(8)));

#define DEVI static __device__ __forceinline__

DEVI ushort f2bf(float f) {
  unsigned u = __builtin_bit_cast(unsigned, f);
  u += 0x7fffu + ((u >> 16) & 1u);
  return (ushort)(u >> 16);
}

DEVI float b2f(ushort u) {
  unsigned x = ((unsigned)u) << 16;
  return __builtin_bit_cast(float, x);
}

DEVI short8 pack8(float4 a, float4 b) {
  union { ushort u[8]; short8 v; } t;
  t.u[0] = f2bf(a.x); t.u[1] = f2bf(a.y); t.u[2] = f2bf(a.z); t.u[3] = f2bf(a.w);
  t.u[4] = f2bf(b.x); t.u[5] = f2bf(b.y); t.u[6] = f2bf(b.z); t.u[7] = f2bf(b.w);
  return t.v;
}

DEVI f32x4 MFMA16(short8 a, short8 b, f32x4 c) {
  return __builtin_amdgcn_mfma_f32_16x16x32_bf16(a, b, c, 0, 0, 0);
}

// async global->LDS DMA, 16B/lane; LDS dest is wave-uniform base (+lane*16 by HW)
DEVI void gld16(const ushort* g, ushort* l) {
  __builtin_amdgcn_global_load_lds(
      (const __attribute__((address_space(1))) unsigned int*)g,
      (__attribute__((address_space(3))) unsigned int*)l, 16, 0, 0);
}

#define VMC0() asm volatile("s_waitcnt vmcnt(0)" ::: "memory")
#define LGK0() asm volatile("s_waitcnt lgkmcnt(0)" ::: "memory")

// ---------------- fused prep: bias (bf16) materialize + 3 bf16 converts ----------------
__global__ void prep_all(const float* __restrict__ table, const int* __restrict__ rel_idx,
                         ushort* __restrict__ bias,
                         const float* __restrict__ x, ushort* __restrict__ xbf,
                         const float* __restrict__ wq, ushort* __restrict__ wqb,
                         const float* __restrict__ wp, ushort* __restrict__ wpb) {
  const int bid = blockIdx.x, tid = threadIdx.x;
  if (bid < 2028) {
    int i = bid * 256 + tid;
    int k = i % 208;
    int t = i / 208;
    int q = t % 208;
    int h = t / 208;
    float v;
    if (k >= 197) v = -1e30f;
    else if (q == 0 || k == 0 || q >= 197) v = 0.0f;
    else v = table[rel_idx[(q - 1) * 196 + (k - 1)] * 12 + h];
    bias[i] = f2bf(v);
  } else if (bid < 6756) {
    int i = (bid - 2028) * 256 + tid;
    float4 a = ((const float4*)x)[i * 2];
    float4 b = ((const float4*)x)[i * 2 + 1];
    ((short8*)xbf)[i] = pack8(a, b);
  } else if (bid < 7620) {
    int i = (bid - 6756) * 256 + tid;
    float4 a = ((const float4*)wq)[i * 2];
    float4 b = ((const float4*)wq)[i * 2 + 1];
    ((short8*)wqb)[i] = pack8(a, b);
  } else {
    int i = (bid - 7620) * 256 + tid;
    float4 a = ((const float4*)wp)[i * 2];
    float4 b = ((const float4*)wp)[i * 2 + 1];
    ((short8*)wpb)[i] = pack8(a, b);
  }
}

// ====== QKV: 128x128, BK=32, dbuf LDS (32KB) -> 4 blocks/CU (proven r4/r10) ======
// drain-0 ledger, T2 both-sides XOR swizzle (measured CONFLICT=0), bijective
// XCD swizzle, 16x16x32 MFMA. VGPR=64, no spill.
__launch_bounds__(256, 4)
__global__ void qkv128(const ushort* __restrict__ A, const ushort* __restrict__ B,
                       ushort* __restrict__ q, ushort* __restrict__ k,
                       ushort* __restrict__ v) {
  __shared__ __align__(16) ushort As[2][4096];  // [128][32] per buf
  __shared__ __align__(16) ushort Bs[2][4096];

  const int tid = threadIdx.x;
  const int lane = tid & 63, wid = tid >> 6;
  const int wm = wid >> 1, wn = wid & 1;
  const int l15 = lane & 15, l4 = lane >> 4;

  const int nwg = gridDim.x;
  const int qc = nwg >> 3, rc = nwg & 7;
  const int xcd = blockIdx.x & 7, sub = blockIdx.x >> 3;
  const int wgid = (xcd < rc ? xcd * (qc + 1) : rc * (qc + 1) + (xcd - rc) * qc) + sub;
  const int bn = wgid % 18, bm = wgid / 18;

  const int c0 = wid * 2, c1 = wid * 2 + 1;
  const int r0 = c0 * 16 + (lane >> 2);
  const int r1 = c1 * 16 + (lane >> 2);
  const int g = lane & 3;
  const int col0 = (g << 3) ^ ((r0 & 6) << 2);  // pre-swizzled source col (elems)
  const int col1 = (g << 3) ^ ((r1 & 6) << 2);
  long ar0 = bm * 128 + r0; if (ar0 > 12607) ar0 = 12607;
  long ar1 = bm * 128 + r1; if (ar1 > 12607) ar1 = 12607;
  const ushort* pA0 = A + ar0 * 768 + col0;
  const ushort* pA1 = A + ar1 * 768 + col1;
  const ushort* pB0 = B + (size_t)(bn * 128 + r0) * 768 + col0;
  const ushort* pB1 = B + (size_t)(bn * 128 + r1) * 768 + col1;

  const int xk = (l4 * 8) ^ ((l15 & 6) << 2);
  int aoff[4], boff[4];
#pragma unroll
  for (int m = 0; m < 4; m++) aoff[m] = (wm * 64 + m * 16 + l15) * 32 + xk;
#pragma unroll
  for (int n = 0; n < 4; n++) boff[n] = (wn * 64 + n * 16 + l15) * 32 + xk;

  f32x4 acc[4][4];
#pragma unroll
  for (int m = 0; m < 4; m++)
#pragma unroll
    for (int n = 0; n < 4; n++) acc[m][n] = (f32x4)0.0f;

#define STAGE(BUF, KO)                          \
  gld16(pA0 + (KO), &As[BUF][c0 * 512]);        \
  gld16(pA1 + (KO), &As[BUF][c1 * 512]);        \
  gld16(pB0 + (KO), &Bs[BUF][c0 * 512]);        \
  gld16(pB1 + (KO), &Bs[BUF][c1 * 512]);

#define COMPUTE(BUF)                                                \
  {                                                                 \
    short8 af[4], bv[4];                                            \
    _Pragma("unroll") for (int m = 0; m < 4; m++)                   \
        af[m] = *(const short8*)&As[BUF][aoff[m]];                  \
    _Pragma("unroll") for (int n = 0; n < 4; n++)                   \
        bv[n] = *(const short8*)&Bs[BUF][boff[n]];                  \
    __builtin_amdgcn_s_setprio(1);                                  \
    _Pragma("unroll") for (int m = 0; m < 4; m++)                   \
        _Pragma("unroll") for (int n = 0; n < 4; n++)               \
            acc[m][n] = MFMA16(af[m], bv[n], acc[m][n]);            \
    __builtin_amdgcn_s_setprio(0);                                  \
  }

  STAGE(0, 0)
  for (int t = 0; t < 23; ++t) {
    VMC0(); LGK0();
    __builtin_amdgcn_s_barrier();
    __builtin_amdgcn_sched_barrier(0);
    STAGE((t + 1) & 1, (t + 1) * 32)
    COMPUTE(t & 1)
  }
  VMC0(); LGK0();
  __builtin_amdgcn_s_barrier();
  __builtin_amdgcn_sched_barrier(0);
  COMPUTE(1)

  const int s = bn / 6;
  ushort* dst = (s == 0) ? q : ((s == 1) ? k : v);
  const float qs = (s == 0) ? 0.125f : 1.0f;
  const int cbase = bn * 128 + wn * 64 - s * 768;  // multiple of 64
  const int hh = cbase >> 6;
#pragma unroll
  for (int m = 0; m < 4; m++) {
#pragma unroll
    for (int r = 0; r < 4; r++) {
      int gm = bm * 128 + wm * 64 + m * 16 + l4 * 4 + r;
      if (gm >= 12608) continue;
      int b = gm / 197;
      int ns = gm - b * 197;
      size_t base = (size_t)((b * 12 + hh) * 197 + ns) * 64;
#pragma unroll
      for (int n = 0; n < 4; n++)
        dst[base + n * 16 + l15] = f2bf(acc[m][n][r] * qs);
    }
  }
#undef STAGE
#undef COMPUTE
}

// ====== Proj: 128x128, BK=64, dbuf LDS (64KB) -> 2 blocks/CU, 12 drains ======
// proj is residency/latency-bound (594 blocks = 2.3/CU of work), so the 64KB
// 2-block cap costs nothing while halving the per-block drain count (24->12).
// 3-bit XOR swizzle for 128B row stride (r9-measured CONFLICT=0 involution):
// LDS cell (row, cg) holds global colgroup cg^(row&7); read cg ^= (l15&7).
// Same drain-0 ledger. launch_bounds(256,2): VGPR cap 256, need ~130 -> no spill.
__launch_bounds__(256, 2)
__global__ void proj128k64(const ushort* __restrict__ A, const ushort* __restrict__ B,
                           const float* __restrict__ bprj, float* __restrict__ out) {
  __shared__ __align__(16) ushort As[2][8192];  // [128][64] per buf
  __shared__ __align__(16) ushort Bs[2][8192];

  const int tid = threadIdx.x;
  const int lane = tid & 63, wid = tid >> 6;
  const int wm = wid >> 1, wn = wid & 1;
  const int l15 = lane & 15, l4 = lane >> 4;

  const int nwg = gridDim.x;
  const int qc = nwg >> 3, rc = nwg & 7;
  const int xcd = blockIdx.x & 7, sub = blockIdx.x >> 3;
  const int wgid = (xcd < rc ? xcd * (qc + 1) : rc * (qc + 1) + (xcd - rc) * qc) + sub;
  const int bn = wgid % 6, bm = wgid / 6;

  // staging: per buf, each tile 128x64 (16KB) = 16 chunks of 1KB (8 rows x 64).
  // wave stages A chunks 4w..4w+3 and B chunks 4w..4w+3 (8 gld16/thread/stage).
  // chunk c, lane: row = c*8 + (lane>>3); colgroup cg = lane&7;
  // source col pre-XOR: (cg ^ (row&7))*8. LDS dest linear (lane*16B by HW).
  const int sr = lane >> 3;          // row-within-chunk = row&7
  const int scg = lane & 7;
  const ushort* pa[4];
  const ushort* pb[4];
  int la[4];
#pragma unroll
  for (int j = 0; j < 4; j++) {
    int c = wid * 4 + j;
    int row = c * 8 + sr;
    int scol = ((scg ^ (row & 7)) << 3);
    long gr = (long)bm * 128 + row;
    if (gr > 12607) gr = 12607;
    pa[j] = A + gr * 768 + scol;
    pb[j] = B + (size_t)(bn * 128 + row) * 768 + scol;
    la[j] = c * 512;
  }

  // fragment-read swizzled colgroup offsets (elems) for K-halves kk=0,1
  // read row & 7 == l15 & 7; colgroup want = kk*4 + l4
  const int rs = l15 & 7;
  const int ck0 = ((l4 ^ rs) << 3);
  const int ck1 = (((4 | l4) ^ rs) << 3);
  int arow[4], brow[4];
#pragma unroll
  for (int m = 0; m < 4; m++) arow[m] = (wm * 64 + m * 16 + l15) * 64;
#pragma unroll
  for (int n = 0; n < 4; n++) brow[n] = (wn * 64 + n * 16 + l15) * 64;

  f32x4 acc[4][4];
#pragma unroll
  for (int m = 0; m < 4; m++)
#pragma unroll
    for (int n = 0; n < 4; n++) acc[m][n] = (f32x4)0.0f;

#define STAGE(BUF, KO)                                            \
  { _Pragma("unroll") for (int j = 0; j < 4; j++) {               \
      gld16(pa[j] + (KO), &As[BUF][la[j]]);                       \
      gld16(pb[j] + (KO), &Bs[BUF][la[j]]);                       \
    } }

#define COMPUTE(BUF)                                                        \
  { _Pragma("unroll") for (int kk = 0; kk < 2; kk++) {                      \
      const int ck = kk ? ck1 : ck0;                                        \
      short8 af[4], bv[4];                                                  \
      _Pragma("unroll") for (int m = 0; m < 4; m++)                         \
        af[m] = *(const short8*)&As[BUF][arow[m] + ck];                     \
      _Pragma("unroll") for (int n = 0; n < 4; n++)                         \
        bv[n] = *(const short8*)&Bs[BUF][brow[n] + ck];                     \
      __builtin_amdgcn_s_setprio(1);                                        \
      _Pragma("unroll") for (int m = 0; m < 4; m++)                         \
        _Pragma("unroll") for (int n = 0; n < 4; n++)                       \
          acc[m][n] = MFMA16(af[m], bv[n], acc[m][n]);                      \
      __builtin_amdgcn_s_setprio(0);                                        \
    } }

  STAGE(0, 0)
  // drain-0 ledger, 12 K-tiles of 64: at top of iter t only stage-t's 8 loads
  // are outstanding (issued a full COMPUTE ago); lgkm(0)+barrier protects the
  // WAR on buf[(t+1)&1].
  for (int t = 0; t < 11; ++t) {
    VMC0(); LGK0();
    __builtin_amdgcn_s_barrier();
    __builtin_amdgcn_sched_barrier(0);
    STAGE((t + 1) & 1, (t + 1) * 64)
    COMPUTE(t & 1)
  }
  VMC0(); LGK0();
  __builtin_amdgcn_s_barrier();
  __builtin_amdgcn_sched_barrier(0);
  COMPUTE(1)

  float bb[4];
#pragma unroll
  for (int n = 0; n < 4; n++) bb[n] = bprj[bn * 128 + wn * 64 + n * 16 + l15];
#pragma unroll
  for (int m = 0; m < 4; m++) {
#pragma unroll
    for (int r = 0; r < 4; r++) {
      int gm = bm * 128 + wm * 64 + m * 16 + l4 * 4 + r;
      if (gm >= 12608) continue;
#pragma unroll
      for (int n = 0; n < 4; n++)
        out[(size_t)gm * 768 + bn * 128 + wn * 64 + n * 16 + l15] = acc[m][n][r] + bb[n];
    }
  }
#undef STAGE
#undef COMPUTE
}

// ---------------- fused attention per (b,h): 13 waves, 1 q-tile per wave ----------------
__launch_bounds__(832)
__global__ void attn(const ushort* __restrict__ qws, const ushort* __restrict__ kws,
                     const ushort* __restrict__ vws, const ushort* __restrict__ biasws,
                     ushort* __restrict__ aout) {
  __shared__ __align__(16) ushort Ks[208 * 72];        // 29,952 B
  __shared__ __align__(16) ushort Vt[64 * 232];        // 29,696 B
  __shared__ __align__(16) ushort Ps[13 * 16 * 232];   // 96,512 B  (total 156,160 <= 160K)

  const int bh = blockIdx.x;
  const int b = bh / 12;
  const int h = bh - b * 12;
  const ushort* qb = qws + (size_t)bh * 197 * 64;
  const ushort* kb = kws + (size_t)bh * 197 * 64;
  const ushort* vb = vws + (size_t)bh * 197 * 64;

  const int tid = threadIdx.x;
  const int lane = tid & 63, wid = tid >> 6;
  const int l15 = lane & 15, l4 = lane >> 4;

  for (int c = tid; c < 208 * 8; c += 832) {
    int n = c >> 3, col = (c & 7) << 3;
    short8 v = (short8)0;
    if (n < 197) v = *(const short8*)(kb + n * 64 + col);
    *(short8*)&Ks[n * 72 + col] = v;
  }
  for (int c = tid; c < 224 * 8; c += 832) {
    int n = c % 224;
    int d0 = (c / 224) << 3;
    ushort tmp[8] = {0, 0, 0, 0, 0, 0, 0, 0};
    if (n < 197) {
      short8 v = *(const short8*)(vb + n * 64 + d0);
#pragma unroll
      for (int j = 0; j < 8; j++) tmp[j] = (ushort)v[j];
    }
#pragma unroll
    for (int j = 0; j < 8; j++) Vt[(d0 + j) * 232 + n] = tmp[j];
  }
  __syncthreads();

  ushort* pb = &Ps[wid * (16 * 232)];
  const ushort* biasb = biasws + (size_t)h * 208 * 208;

  {
    const int t = wid;  // one q-tile per wave, 13 waves
    const int q0 = t * 16;
    int qr = q0 + l15; if (qr > 196) qr = 196;
    short8 aq0 = *(const short8*)(qb + qr * 64 + (l4 << 3));
    short8 aq1 = *(const short8*)(qb + qr * 64 + 32 + (l4 << 3));

    f32x4 sc[13];
    __builtin_amdgcn_s_setprio(1);
#pragma unroll
    for (int ct = 0; ct < 13; ct++) {
      short8 b0 = *(const short8*)&Ks[(ct * 16 + l15) * 72 + (l4 << 3)];
      short8 b1 = *(const short8*)&Ks[(ct * 16 + l15) * 72 + 32 + (l4 << 3)];
      f32x4 s = (f32x4)0.0f;
      s = MFMA16(aq0, b0, s);
      s = MFMA16(aq1, b1, s);
      sc[ct] = s;
    }
    __builtin_amdgcn_s_setprio(0);

    float mx[4] = {-1e38f, -1e38f, -1e38f, -1e38f};
#pragma unroll
    for (int ct = 0; ct < 13; ct++) {
#pragma unroll
      for (int r = 0; r < 4; r++) {
        float bv = b2f(biasb[(q0 + l4 * 4 + r) * 208 + ct * 16 + l15]);
        float v = sc[ct][r] + bv;
        sc[ct][r] = v;
        mx[r] = fmaxf(mx[r], v);
      }
    }
#pragma unroll
    for (int r = 0; r < 4; r++) {
      mx[r] = fmaxf(mx[r], __shfl_xor(mx[r], 1));
      mx[r] = fmaxf(mx[r], __shfl_xor(mx[r], 2));
      mx[r] = fmaxf(mx[r], __shfl_xor(mx[r], 4));
      mx[r] = fmaxf(mx[r], __shfl_xor(mx[r], 8));
    }
    float sum[4] = {0.f, 0.f, 0.f, 0.f};
#pragma unroll
    for (int ct = 0; ct < 13; ct++) {
#pragma unroll
      for (int r = 0; r < 4; r++) {
        float p = __expf(sc[ct][r] - mx[r]);
        sc[ct][r] = p;
        sum[r] += p;
      }
    }
#pragma unroll
    for (int r = 0; r < 4; r++) {
      sum[r] += __shfl_xor(sum[r], 1);
      sum[r] += __shfl_xor(sum[r], 2);
      sum[r] += __shfl_xor(sum[r], 4);
      sum[r] += __shfl_xor(sum[r], 8);
    }

#pragma unroll
    for (int ct = 0; ct < 13; ct++)
#pragma unroll
      for (int r = 0; r < 4; r++)
        pb[(l4 * 4 + r) * 232 + ct * 16 + l15] = f2bf(sc[ct][r]);
#pragma unroll
    for (int r = 0; r < 4; r++)
      pb[(l4 * 4 + r) * 232 + 208 + l15] = 0;

    short8 pa[7];
#pragma unroll
    for (int kk = 0; kk < 7; kk++)
      pa[kk] = *(const short8*)&pb[l15 * 232 + kk * 32 + (l4 << 3)];
    f32x4 o[4];
    __builtin_amdgcn_s_setprio(1);
#pragma unroll
    for (int dt = 0; dt < 4; dt++) {
      f32x4 acc = (f32x4)0.0f;
#pragma unroll
      for (int kk = 0; kk < 7; kk++) {
        short8 bv = *(const short8*)&Vt[(dt * 16 + l15) * 232 + kk * 32 + (l4 << 3)];
        acc = MFMA16(pa[kk], bv, acc);
      }
      o[dt] = acc;
    }
    __builtin_amdgcn_s_setprio(0);

    float rs[4];
#pragma unroll
    for (int r = 0; r < 4; r++) rs[r] = 1.0f / sum[r];
#pragma unroll
    for (int dt = 0; dt < 4; dt++) {
#pragma unroll
      for (int r = 0; r < 4; r++) {
        int row = q0 + l4 * 4 + r;
        if (row < 197) {
          float v = o[dt][r] * rs[r];
          aout[(size_t)(b * 197 + row) * 768 + h * 64 + dt * 16 + l15] = f2bf(v);
        }
      }
    }
  }
}

extern "C" void kernel_launch(void* const* d_in, const int* in_sizes, int n_in,
                              void* d_out, int out_size, void* d_ws, size_t ws_size,
                              hipStream_t stream) {
  const float* x      = (const float*)d_in[0];
  const float* w_qkv  = (const float*)d_in[1];
  const float* w_proj = (const float*)d_in[2];
  const float* b_proj = (const float*)d_in[3];
  const float* rpb    = (const float*)d_in[4];
  const int*   relidx = (const int*)d_in[5];
  float* out = (float*)d_out;

  char* ws = (char*)d_ws;
  const size_t HB = (size_t)12608 * 768 * 2;  // 19,365,888 B
  ushort* xbf   = (ushort*)(ws);              // aliased by aout after qkv is consumed
  ushort* qws   = (ushort*)(ws + HB);
  ushort* kws   = (ushort*)(ws + 2 * HB);
  ushort* vws   = (ushort*)(ws + 3 * HB);
  ushort* bias  = (ushort*)(ws + 4 * HB);                      // bf16, 1,038,336 B (slot 2 MB)
  ushort* wqkvb = (ushort*)(ws + 4 * HB + 2076672);            // 3,538,944 B
  ushort* wprjb = (ushort*)(ws + 4 * HB + 2076672 + 3538944);  // 1,179,648 B
  ushort* aout  = xbf;

  hipLaunchKernelGGL(prep_all, dim3(7908), dim3(256), 0, stream,
                     rpb, relidx, bias, x, xbf, w_qkv, wqkvb, w_proj, wprjb);
  hipLaunchKernelGGL(qkv128, dim3(18 * 99), dim3(256), 0, stream,
                     xbf, wqkvb, qws, kws, vws);
  hipLaunchKernelGGL(attn, dim3(768), dim3(832), 0, stream, qws, kws, vws, bias, aout);
  hipLaunchKernelGGL(proj128k64, dim3(6 * 99), dim3(256), 0, stream,
                     aout, wprjb, b_proj, out);
}

// Round 17
// 132.227 us; speedup vs baseline: 1.0515x; 1.0515x over previous
//
#include <hip/hip_runtime.h>

typedef float f32x4 __attribute__((ext_vector_type(4)));
typedef short short8 __attribute__((ext_vector_type(8)));

#define DEVI static __device__ __forceinline__

DEVI ushort f2bf(float f) {
  unsigned u = __builtin_bit_cast(unsigned, f);
  u += 0x7fffu + ((u >> 16) & 1u);
  return (ushort)(u >> 16);
}

DEVI float b2f(ushort u) {
  unsigned x = ((unsigned)u) << 16;
  return __builtin_bit_cast(float, x);
}

DEVI short8 pack8(float4 a, float4 b) {
  union { ushort u[8]; short8 v; } t;
  t.u[0] = f2bf(a.x); t.u[1] = f2bf(a.y); t.u[2] = f2bf(a.z); t.u[3] = f2bf(a.w);
  t.u[4] = f2bf(b.x); t.u[5] = f2bf(b.y); t.u[6] = f2bf(b.z); t.u[7] = f2bf(b.w);
  return t.v;
}

DEVI f32x4 MFMA16(short8 a, short8 b, f32x4 c) {
  return __builtin_amdgcn_mfma_f32_16x16x32_bf16(a, b, c, 0, 0, 0);
}

// async global->LDS DMA, 16B/lane; LDS dest is wave-uniform base (+lane*16 by HW)
DEVI void gld16(const ushort* g, ushort* l) {
  __builtin_amdgcn_global_load_lds(
      (const __attribute__((address_space(1))) unsigned int*)g,
      (__attribute__((address_space(3))) unsigned int*)l, 16, 0, 0);
}

#define VMC0() asm volatile("s_waitcnt vmcnt(0)" ::: "memory")
#define LGK0() asm volatile("s_waitcnt lgkmcnt(0)" ::: "memory")

// ---------------- fused prep: bias (bf16) materialize + 3 bf16 converts ----------------
__global__ void prep_all(const float* __restrict__ table, const int* __restrict__ rel_idx,
                         ushort* __restrict__ bias,
                         const float* __restrict__ x, ushort* __restrict__ xbf,
                         const float* __restrict__ wq, ushort* __restrict__ wqb,
                         const float* __restrict__ wp, ushort* __restrict__ wpb) {
  const int bid = blockIdx.x, tid = threadIdx.x;
  if (bid < 2028) {
    int i = bid * 256 + tid;
    int k = i % 208;
    int t = i / 208;
    int q = t % 208;
    int h = t / 208;
    float v;
    if (k >= 197) v = -1e30f;
    else if (q == 0 || k == 0 || q >= 197) v = 0.0f;
    else v = table[rel_idx[(q - 1) * 196 + (k - 1)] * 12 + h];
    bias[i] = f2bf(v);
  } else if (bid < 6756) {
    int i = (bid - 2028) * 256 + tid;
    float4 a = ((const float4*)x)[i * 2];
    float4 b = ((const float4*)x)[i * 2 + 1];
    ((short8*)xbf)[i] = pack8(a, b);
  } else if (bid < 7620) {
    int i = (bid - 6756) * 256 + tid;
    float4 a = ((const float4*)wq)[i * 2];
    float4 b = ((const float4*)wq)[i * 2 + 1];
    ((short8*)wqb)[i] = pack8(a, b);
  } else {
    int i = (bid - 7620) * 256 + tid;
    float4 a = ((const float4*)wp)[i * 2];
    float4 b = ((const float4*)wp)[i * 2 + 1];
    ((short8*)wpb)[i] = pack8(a, b);
  }
}

// ====== 128x128 GEMM, BK=32, double-buffered LDS (32KB) -> 4 blocks/CU ======
// Proven best (r4/r10/r13/r15, benched 132.5us x3): drain-0 ledger, T2
// both-sides XOR swizzle (measured CONFLICT=0), bijective XCD swizzle,
// 16x16x32 MFMA. VGPR=64, no spill.
// MODE 0: qkv (A=xbf [12608,768], B=wqkv [2304,768]^T, scatter bf16 q/k/v)
// MODE 1: proj (A=aout [12608,768], B=wproj [768,768]^T, +bias -> fp32 out)
template <int MODE, int NBN>
__launch_bounds__(256, 4)
__global__ void gemm128(const ushort* __restrict__ A, const ushort* __restrict__ B,
                        ushort* __restrict__ q, ushort* __restrict__ k,
                        ushort* __restrict__ v,
                        const float* __restrict__ bprj, float* __restrict__ out) {
  __shared__ __align__(16) ushort As[2][4096];  // [128][32] per buf
  __shared__ __align__(16) ushort Bs[2][4096];

  const int tid = threadIdx.x;
  const int lane = tid & 63, wid = tid >> 6;
  const int wm = wid >> 1, wn = wid & 1;
  const int l15 = lane & 15, l4 = lane >> 4;

  // bijective XCD swizzle: same-XCD blocks get a contiguous wgid chunk
  const int nwg = gridDim.x;
  const int qc = nwg >> 3, rc = nwg & 7;
  const int xcd = blockIdx.x & 7, sub = blockIdx.x >> 3;
  const int wgid = (xcd < rc ? xcd * (qc + 1) : rc * (qc + 1) + (xcd - rc) * qc) + sub;
  const int bn = wgid % NBN, bm = wgid / NBN;

  // staging: per buf, tile 128x32 (8KB) = 8 chunks of 1KB; wave stages chunks 2w,2w+1
  const int c0 = wid * 2, c1 = wid * 2 + 1;
  const int r0 = c0 * 16 + (lane >> 2);
  const int r1 = c1 * 16 + (lane >> 2);
  const int g = lane & 3;
  const int col0 = (g << 3) ^ ((r0 & 6) << 2);  // pre-swizzled source col (elems)
  const int col1 = (g << 3) ^ ((r1 & 6) << 2);
  long ar0 = bm * 128 + r0; if (ar0 > 12607) ar0 = 12607;
  long ar1 = bm * 128 + r1; if (ar1 > 12607) ar1 = 12607;
  const ushort* pA0 = A + ar0 * 768 + col0;
  const ushort* pA1 = A + ar1 * 768 + col1;
  const ushort* pB0 = B + (size_t)(bn * 128 + r0) * 768 + col0;
  const ushort* pB1 = B + (size_t)(bn * 128 + r1) * 768 + col1;

  // swizzled fragment-read offsets (elems); 2-way conflict max (free)
  const int xk = (l4 * 8) ^ ((l15 & 6) << 2);
  int aoff[4], boff[4];
#pragma unroll
  for (int m = 0; m < 4; m++) aoff[m] = (wm * 64 + m * 16 + l15) * 32 + xk;
#pragma unroll
  for (int n = 0; n < 4; n++) boff[n] = (wn * 64 + n * 16 + l15) * 32 + xk;

  f32x4 acc[4][4];
#pragma unroll
  for (int m = 0; m < 4; m++)
#pragma unroll
    for (int n = 0; n < 4; n++) acc[m][n] = (f32x4)0.0f;

#define STAGE(BUF, KO)                          \
  gld16(pA0 + (KO), &As[BUF][c0 * 512]);        \
  gld16(pA1 + (KO), &As[BUF][c1 * 512]);        \
  gld16(pB0 + (KO), &Bs[BUF][c0 * 512]);        \
  gld16(pB1 + (KO), &Bs[BUF][c1 * 512]);

#define COMPUTE(BUF)                                                \
  {                                                                 \
    short8 af[4], bv[4];                                            \
    _Pragma("unroll") for (int m = 0; m < 4; m++)                   \
        af[m] = *(const short8*)&As[BUF][aoff[m]];                  \
    _Pragma("unroll") for (int n = 0; n < 4; n++)                   \
        bv[n] = *(const short8*)&Bs[BUF][boff[n]];                  \
    __builtin_amdgcn_s_setprio(1);                                  \
    _Pragma("unroll") for (int m = 0; m < 4; m++)                   \
        _Pragma("unroll") for (int n = 0; n < 4; n++)               \
            acc[m][n] = MFMA16(af[m], bv[n], acc[m][n]);            \
    __builtin_amdgcn_s_setprio(0);                                  \
  }

  STAGE(0, 0)
  // ledger: at top of iter t, only stage-t loads are outstanding (issued last
  // iter, a full COMPUTE ago) -> vmcnt(0) cheap; lgkm(0) before barrier
  // guarantees my reads of buf[~cur] finished before anyone overwrites it.
  for (int t = 0; t < 23; ++t) {
    VMC0(); LGK0();
    __builtin_amdgcn_s_barrier();
    __builtin_amdgcn_sched_barrier(0);
    STAGE((t + 1) & 1, (t + 1) * 32)
    COMPUTE(t & 1)
  }
  VMC0(); LGK0();
  __builtin_amdgcn_s_barrier();
  __builtin_amdgcn_sched_barrier(0);
  COMPUTE(1)

  // ---------------- epilogue ----------------
  if (MODE == 0) {
    const int s = bn / 6;
    ushort* dst = (s == 0) ? q : ((s == 1) ? k : v);
    const float qs = (s == 0) ? 0.125f : 1.0f;
    const int cbase = bn * 128 + wn * 64 - s * 768;  // multiple of 64
    const int hh = cbase >> 6;
#pragma unroll
    for (int m = 0; m < 4; m++) {
#pragma unroll
      for (int r = 0; r < 4; r++) {
        int gm = bm * 128 + wm * 64 + m * 16 + l4 * 4 + r;
        if (gm >= 12608) continue;
        int b = gm / 197;
        int ns = gm - b * 197;
        size_t base = (size_t)((b * 12 + hh) * 197 + ns) * 64;
#pragma unroll
        for (int n = 0; n < 4; n++)
          dst[base + n * 16 + l15] = f2bf(acc[m][n][r] * qs);
      }
    }
  } else {
    float bb[4];
#pragma unroll
    for (int n = 0; n < 4; n++) bb[n] = bprj[bn * 128 + wn * 64 + n * 16 + l15];
#pragma unroll
    for (int m = 0; m < 4; m++) {
#pragma unroll
      for (int r = 0; r < 4; r++) {
        int gm = bm * 128 + wm * 64 + m * 16 + l4 * 4 + r;
        if (gm >= 12608) continue;
#pragma unroll
        for (int n = 0; n < 4; n++)
          out[(size_t)gm * 768 + bn * 128 + wn * 64 + n * 16 + l15] = acc[m][n][r] + bb[n];
      }
    }
  }
#undef STAGE
#undef COMPUTE
}

// ---------------- fused attention per (b,h): 13 waves, 1 q-tile per wave ----------------
__launch_bounds__(832)
__global__ void attn(const ushort* __restrict__ qws, const ushort* __restrict__ kws,
                     const ushort* __restrict__ vws, const ushort* __restrict__ biasws,
                     ushort* __restrict__ aout) {
  __shared__ __align__(16) ushort Ks[208 * 72];        // 29,952 B
  __shared__ __align__(16) ushort Vt[64 * 232];        // 29,696 B
  __shared__ __align__(16) ushort Ps[13 * 16 * 232];   // 96,512 B  (total 156,160 <= 160K)

  const int bh = blockIdx.x;
  const int b = bh / 12;
  const int h = bh - b * 12;
  const ushort* qb = qws + (size_t)bh * 197 * 64;
  const ushort* kb = kws + (size_t)bh * 197 * 64;
  const ushort* vb = vws + (size_t)bh * 197 * 64;

  const int tid = threadIdx.x;
  const int lane = tid & 63, wid = tid >> 6;
  const int l15 = lane & 15, l4 = lane >> 4;

  for (int c = tid; c < 208 * 8; c += 832) {
    int n = c >> 3, col = (c & 7) << 3;
    short8 v = (short8)0;
    if (n < 197) v = *(const short8*)(kb + n * 64 + col);
    *(short8*)&Ks[n * 72 + col] = v;
  }
  for (int c = tid; c < 224 * 8; c += 832) {
    int n = c % 224;
    int d0 = (c / 224) << 3;
    ushort tmp[8] = {0, 0, 0, 0, 0, 0, 0, 0};
    if (n < 197) {
      short8 v = *(const short8*)(vb + n * 64 + d0);
#pragma unroll
      for (int j = 0; j < 8; j++) tmp[j] = (ushort)v[j];
    }
#pragma unroll
    for (int j = 0; j < 8; j++) Vt[(d0 + j) * 232 + n] = tmp[j];
  }
  __syncthreads();

  ushort* pb = &Ps[wid * (16 * 232)];
  const ushort* biasb = biasws + (size_t)h * 208 * 208;

  {
    const int t = wid;  // one q-tile per wave, 13 waves
    const int q0 = t * 16;
    int qr = q0 + l15; if (qr > 196) qr = 196;
    short8 aq0 = *(const short8*)(qb + qr * 64 + (l4 << 3));
    short8 aq1 = *(const short8*)(qb + qr * 64 + 32 + (l4 << 3));

    f32x4 sc[13];
    __builtin_amdgcn_s_setprio(1);
#pragma unroll
    for (int ct = 0; ct < 13; ct++) {
      short8 b0 = *(const short8*)&Ks[(ct * 16 + l15) * 72 + (l4 << 3)];
      short8 b1 = *(const short8*)&Ks[(ct * 16 + l15) * 72 + 32 + (l4 << 3)];
      f32x4 s = (f32x4)0.0f;
      s = MFMA16(aq0, b0, s);
      s = MFMA16(aq1, b1, s);
      sc[ct] = s;
    }
    __builtin_amdgcn_s_setprio(0);

    float mx[4] = {-1e38f, -1e38f, -1e38f, -1e38f};
#pragma unroll
    for (int ct = 0; ct < 13; ct++) {
#pragma unroll
      for (int r = 0; r < 4; r++) {
        float bv = b2f(biasb[(q0 + l4 * 4 + r) * 208 + ct * 16 + l15]);
        float v = sc[ct][r] + bv;
        sc[ct][r] = v;
        mx[r] = fmaxf(mx[r], v);
      }
    }
#pragma unroll
    for (int r = 0; r < 4; r++) {
      mx[r] = fmaxf(mx[r], __shfl_xor(mx[r], 1));
      mx[r] = fmaxf(mx[r], __shfl_xor(mx[r], 2));
      mx[r] = fmaxf(mx[r], __shfl_xor(mx[r], 4));
      mx[r] = fmaxf(mx[r], __shfl_xor(mx[r], 8));
    }
    float sum[4] = {0.f, 0.f, 0.f, 0.f};
#pragma unroll
    for (int ct = 0; ct < 13; ct++) {
#pragma unroll
      for (int r = 0; r < 4; r++) {
        float p = __expf(sc[ct][r] - mx[r]);
        sc[ct][r] = p;
        sum[r] += p;
      }
    }
#pragma unroll
    for (int r = 0; r < 4; r++) {
      sum[r] += __shfl_xor(sum[r], 1);
      sum[r] += __shfl_xor(sum[r], 2);
      sum[r] += __shfl_xor(sum[r], 4);
      sum[r] += __shfl_xor(sum[r], 8);
    }

#pragma unroll
    for (int ct = 0; ct < 13; ct++)
#pragma unroll
      for (int r = 0; r < 4; r++)
        pb[(l4 * 4 + r) * 232 + ct * 16 + l15] = f2bf(sc[ct][r]);
#pragma unroll
    for (int r = 0; r < 4; r++)
      pb[(l4 * 4 + r) * 232 + 208 + l15] = 0;

    short8 pa[7];
#pragma unroll
    for (int kk = 0; kk < 7; kk++)
      pa[kk] = *(const short8*)&pb[l15 * 232 + kk * 32 + (l4 << 3)];
    f32x4 o[4];
    __builtin_amdgcn_s_setprio(1);
#pragma unroll
    for (int dt = 0; dt < 4; dt++) {
      f32x4 acc = (f32x4)0.0f;
#pragma unroll
      for (int kk = 0; kk < 7; kk++) {
        short8 bv = *(const short8*)&Vt[(dt * 16 + l15) * 232 + kk * 32 + (l4 << 3)];
        acc = MFMA16(pa[kk], bv, acc);
      }
      o[dt] = acc;
    }
    __builtin_amdgcn_s_setprio(0);

    float rs[4];
#pragma unroll
    for (int r = 0; r < 4; r++) rs[r] = 1.0f / sum[r];
#pragma unroll
    for (int dt = 0; dt < 4; dt++) {
#pragma unroll
      for (int r = 0; r < 4; r++) {
        int row = q0 + l4 * 4 + r;
        if (row < 197) {
          float v = o[dt][r] * rs[r];
          aout[(size_t)(b * 197 + row) * 768 + h * 64 + dt * 16 + l15] = f2bf(v);
        }
      }
    }
  }
}

extern "C" void kernel_launch(void* const* d_in, const int* in_sizes, int n_in,
                              void* d_out, int out_size, void* d_ws, size_t ws_size,
                              hipStream_t stream) {
  const float* x      = (const float*)d_in[0];
  const float* w_qkv  = (const float*)d_in[1];
  const float* w_proj = (const float*)d_in[2];
  const float* b_proj = (const float*)d_in[3];
  const float* rpb    = (const float*)d_in[4];
  const int*   relidx = (const int*)d_in[5];
  float* out = (float*)d_out;

  char* ws = (char*)d_ws;
  const size_t HB = (size_t)12608 * 768 * 2;  // 19,365,888 B
  ushort* xbf   = (ushort*)(ws);              // aliased by aout after qkv is consumed
  ushort* qws   = (ushort*)(ws + HB);
  ushort* kws   = (ushort*)(ws + 2 * HB);
  ushort* vws   = (ushort*)(ws + 3 * HB);
  ushort* bias  = (ushort*)(ws + 4 * HB);                      // bf16, 1,038,336 B (slot 2 MB)
  ushort* wqkvb = (ushort*)(ws + 4 * HB + 2076672);            // 3,538,944 B
  ushort* wprjb = (ushort*)(ws + 4 * HB + 2076672 + 3538944);  // 1,179,648 B
  ushort* aout  = xbf;

  hipLaunchKernelGGL(prep_all, dim3(7908), dim3(256), 0, stream,
                     rpb, relidx, bias, x, xbf, w_qkv, wqkvb, w_proj, wprjb);
  hipLaunchKernelGGL((gemm128<0, 18>), dim3(18 * 99), dim3(256), 0, stream,
                     xbf, wqkvb, qws, kws, vws, nullptr, nullptr);
  hipLaunchKernelGGL(attn, dim3(768), dim3(832), 0, stream, qws, kws, vws, bias, aout);
  hipLaunchKernelGGL((gemm128<1, 6>), dim3(6 * 99), dim3(256), 0, stream,
                     aout, wprjb, nullptr, nullptr, nullptr, b_proj, out);
}